// Round 13
// baseline (131.822 us; speedup 1.0000x reference)
//
#include <hip/hip_runtime.h>

// B=2, T=2048, C=1024, H=16, HD=64. Inputs f32, output f32.
// convert3, QKV GEMM (dbuf-prefetch K-loop) + fused RoPE/split epilogue
// (V^T slot-ordered), flash attention (r12), proj GEMM (dbuf) -> f32.
// ws plan (48 MiB): [0,8M) xb | [8,14M) wqkvb | [14,16M) wprojb | [16,24M) qro
//                   | [24,32M) kro | [32,40M) vt | [40,48M) oat

typedef short  bf16x8 __attribute__((ext_vector_type(8)));
typedef float  f32x4  __attribute__((ext_vector_type(4)));
typedef unsigned short u16x4 __attribute__((ext_vector_type(4)));

#define B_  2
#define T_  2048
#define H_  16
#define HD_ 64
#define NINF (-__builtin_inff())

static __device__ __forceinline__ unsigned short f2bf(float f) {
    union { float f; unsigned u; } v; v.f = f;
    unsigned r = v.u + 0x7fffu + ((v.u >> 16) & 1u);   // RNE
    return (unsigned short)(r >> 16);
}

#define GLOAD_LDS16(gp, lp)                                                              \
    __builtin_amdgcn_global_load_lds((const __attribute__((address_space(1))) void*)(gp), \
                                     (__attribute__((address_space(3))) void*)(lp), 16, 0, 0)

// ---------------- single-launch f32 -> bf16 convert of x, W_qkv, W_proj ----------------
__global__ void convert3(const float* __restrict__ x, const float* __restrict__ wqkv,
                         const float* __restrict__ wproj,
                         unsigned short* __restrict__ xb, unsigned short* __restrict__ wqkvb,
                         unsigned short* __restrict__ wprojb) {
    int i = blockIdx.x * blockDim.x + threadIdx.x;     // float4 index, total 2097152
    const float* src; unsigned short* dst; int off;
    if (i < 1048576)      { src = x;     dst = xb;     off = i; }
    else if (i < 1835008) { src = wqkv;  dst = wqkvb;  off = i - 1048576; }
    else                  { src = wproj; dst = wprojb; off = i - 1835008; }
    float4 f = ((const float4*)src)[off];
    u16x4 o; o[0] = f2bf(f.x); o[1] = f2bf(f.y); o[2] = f2bf(f.z); o[3] = f2bf(f.w);
    ((u16x4*)dst)[off] = o;
}

// ---------------- QKV GEMM (dbuf-prefetch) with fused RoPE+split epilogue ----------------
// cols [0,1024): Q+RoPE -> Qo (B,H,T,64); [1024,2048): K+RoPE -> Ko;
// [2048,3072): V -> Vt (B,H,64,T), keys slot-permuted per 32-block:
// pos(k) = 8*((k&15)>>2) + 4*(k>>4) + (k&3).
__global__ __launch_bounds__(256) void gemm_qkv(const unsigned short* __restrict__ A,
                                                const unsigned short* __restrict__ Bm,
                                                const float* __restrict__ fa,
                                                const float* __restrict__ fb,
                                                unsigned short* __restrict__ Qo,
                                                unsigned short* __restrict__ Ko,
                                                unsigned short* __restrict__ Vt) {
    __shared__ __align__(16) unsigned short As[2][4096];   // dbuf 128x32
    __shared__ __align__(16) unsigned short Bs[2][4096];
    const int K = 1024;
    const int tid  = threadIdx.x;
    const int w    = tid >> 6;
    const int lane = tid & 63;
    const int r    = lane & 15, g = lane >> 4;
    const int m0   = blockIdx.y * 128;
    const int n0   = blockIdx.x * 128;
    const int wm   = (w >> 1) * 64, wn = (w & 1) * 64;

    f32x4 acc[4][4];
#pragma unroll
    for (int i = 0; i < 4; i++)
#pragma unroll
        for (int j = 0; j < 4; j++) acc[i][j] = (f32x4){0.f, 0.f, 0.f, 0.f};

    const int u0 = tid, u1 = 256 + tid;
    const unsigned short* ga0 = A  + (size_t)(m0 + (u0 >> 2)) * K + (u0 & 3) * 8;
    const unsigned short* ga1 = A  + (size_t)(m0 + (u1 >> 2)) * K + (u1 & 3) * 8;
    const unsigned short* gb0 = Bm + (size_t)(n0 + (u0 >> 2)) * K + (u0 & 3) * 8;
    const unsigned short* gb1 = Bm + (size_t)(n0 + (u1 >> 2)) * K + (u1 & 3) * 8;
    const int lws = w * 512;                    // wave-uniform LDS unit base (elems)

#define STAGE_G(bb, k0_)                                            \
    do {                                                            \
        GLOAD_LDS16(ga0 + (k0_), &As[bb][lws]);                     \
        GLOAD_LDS16(ga1 + (k0_), &As[bb][2048 + lws]);              \
        GLOAD_LDS16(gb0 + (k0_), &Bs[bb][lws]);                     \
        GLOAD_LDS16(gb1 + (k0_), &Bs[bb][2048 + lws]);              \
    } while (0)

    STAGE_G(0, 0);
    __syncthreads();                            // tile 0 ready

    for (int k0 = 0; k0 < K; k0 += 32) {
        const int cur = (k0 >> 5) & 1;
        if (k0 + 32 < K) STAGE_G(cur ^ 1, k0 + 32);   // prefetch next tile

        bf16x8 a[4], b[4];
#pragma unroll
        for (int mi = 0; mi < 4; mi++) a[mi] = *(const bf16x8*)&As[cur][(wm + mi * 16 + r) * 32 + 8 * g];
#pragma unroll
        for (int ni = 0; ni < 4; ni++) b[ni] = *(const bf16x8*)&Bs[cur][(wn + ni * 16 + r) * 32 + 8 * g];
#pragma unroll
        for (int mi = 0; mi < 4; mi++)
#pragma unroll
            for (int ni = 0; ni < 4; ni++)
                acc[mi][ni] = __builtin_amdgcn_mfma_f32_16x16x32_bf16(a[mi], b[ni], acc[mi][ni], 0, 0, 0);

        __syncthreads();                        // drains vmcnt (next tile) + read fence
    }
#undef STAGE_G

    // -------- fused epilogue --------
    const float* fcos = (fa[0] > 0.5f) ? fa : fb;   // cos row at t=0 is all 1.0
    const float* fsin = (fa[0] > 0.5f) ? fb : fa;
    const int region = n0 >> 10;                    // 0=Q, 1=K, 2=V (block-uniform)

    if (region < 2) {
        unsigned short* dst = region ? Ko : Qo;
        const float sgn = (r & 1) ? 1.f : -1.f;     // out = v*c + sgn*vp*s
#pragma unroll
        for (int mi = 0; mi < 4; mi++) {
            int row0 = m0 + wm + mi * 16 + 4 * g;
            int b    = row0 >> 11;
            int t0   = row0 & 2047;
#pragma unroll
            for (int ni = 0; ni < 4; ni++) {
                int nn = (n0 & 1023) + wn + ni * 16 + r;
                int h  = nn >> 6, dd = nn & 63;
                int i  = dd >> 1;
                size_t obase = ((size_t)((b * 16 + h) * 2048 + t0)) * 64 + dd;
#pragma unroll
                for (int j = 0; j < 4; j++) {
                    float c = fcos[(t0 + j) * 32 + i];
                    float s = fsin[(t0 + j) * 32 + i];
                    float v  = acc[mi][ni][j];
                    float vp = __shfl_xor(v, 1);
                    float out = __builtin_fmaf(sgn * vp, s, v * c);
                    dst[obase + (size_t)j * 64] = f2bf(out);
                }
            }
        }
    } else {
#pragma unroll
        for (int mi = 0; mi < 4; mi++) {
            int row0 = m0 + wm + mi * 16 + 4 * g;
            int b    = row0 >> 11;
            int t0   = row0 & 2047;
            // key permutation within 32-block (t0 aligned to 4):
            int tp   = (t0 & ~31) + 8 * ((t0 & 15) >> 2) + 4 * ((t0 & 31) >> 4);
#pragma unroll
            for (int ni = 0; ni < 4; ni++) {
                int nn = (n0 & 1023) + wn + ni * 16 + r;
                int h  = nn >> 6, dd = nn & 63;
                u16x4 ov;
#pragma unroll
                for (int j = 0; j < 4; j++) ov[j] = f2bf(acc[mi][ni][j]);
                *(u16x4*)(Vt + ((size_t)((b * 16 + h) * 64 + dd)) * 2048 + tp) = ov;
            }
        }
    }
}

// ---------------- proj GEMM (dbuf-prefetch): C = A*B^T + bias -> f32 ----------------
__global__ __launch_bounds__(256) void gemm_nt(const unsigned short* __restrict__ A,
                                               const unsigned short* __restrict__ Bm,
                                               float* __restrict__ Cm,
                                               const float* __restrict__ bias,
                                               int M, int N, int K) {
    __shared__ __align__(16) unsigned short As[2][4096];
    __shared__ __align__(16) unsigned short Bs[2][4096];
    const int tid  = threadIdx.x;
    const int w    = tid >> 6;
    const int lane = tid & 63;
    const int r    = lane & 15, g = lane >> 4;
    const int m0   = blockIdx.y * 128;
    const int n0   = blockIdx.x * 128;
    const int wm   = (w >> 1) * 64, wn = (w & 1) * 64;

    f32x4 acc[4][4];
#pragma unroll
    for (int i = 0; i < 4; i++)
#pragma unroll
        for (int j = 0; j < 4; j++) acc[i][j] = (f32x4){0.f, 0.f, 0.f, 0.f};

    const int u0 = tid, u1 = 256 + tid;
    const unsigned short* ga0 = A  + (size_t)(m0 + (u0 >> 2)) * K + (u0 & 3) * 8;
    const unsigned short* ga1 = A  + (size_t)(m0 + (u1 >> 2)) * K + (u1 & 3) * 8;
    const unsigned short* gb0 = Bm + (size_t)(n0 + (u0 >> 2)) * K + (u0 & 3) * 8;
    const unsigned short* gb1 = Bm + (size_t)(n0 + (u1 >> 2)) * K + (u1 & 3) * 8;
    const int lws = w * 512;

#define STAGE_G(bb, k0_)                                            \
    do {                                                            \
        GLOAD_LDS16(ga0 + (k0_), &As[bb][lws]);                     \
        GLOAD_LDS16(ga1 + (k0_), &As[bb][2048 + lws]);              \
        GLOAD_LDS16(gb0 + (k0_), &Bs[bb][lws]);                     \
        GLOAD_LDS16(gb1 + (k0_), &Bs[bb][2048 + lws]);              \
    } while (0)

    STAGE_G(0, 0);
    __syncthreads();

    for (int k0 = 0; k0 < K; k0 += 32) {
        const int cur = (k0 >> 5) & 1;
        if (k0 + 32 < K) STAGE_G(cur ^ 1, k0 + 32);

        bf16x8 a[4], b[4];
#pragma unroll
        for (int mi = 0; mi < 4; mi++) a[mi] = *(const bf16x8*)&As[cur][(wm + mi * 16 + r) * 32 + 8 * g];
#pragma unroll
        for (int ni = 0; ni < 4; ni++) b[ni] = *(const bf16x8*)&Bs[cur][(wn + ni * 16 + r) * 32 + 8 * g];
#pragma unroll
        for (int mi = 0; mi < 4; mi++)
#pragma unroll
            for (int ni = 0; ni < 4; ni++)
                acc[mi][ni] = __builtin_amdgcn_mfma_f32_16x16x32_bf16(a[mi], b[ni], acc[mi][ni], 0, 0, 0);

        __syncthreads();
    }
#undef STAGE_G

#pragma unroll
    for (int mi = 0; mi < 4; mi++) {
        int row = m0 + wm + mi * 16 + 4 * g;
#pragma unroll
        for (int ni = 0; ni < 4; ni++) {
            int col = n0 + wn + ni * 16 + r;
            float bv = bias[col];
#pragma unroll
            for (int j = 0; j < 4; j++)
                Cm[(size_t)(row + j) * N + col] = acc[mi][ni][j] + bv;
        }
    }
}

// ---------------- flash attention (round-12 structure, unchanged) ----------------
static __device__ __forceinline__ int swzb(int row, int chunk) {   // LDS byte offset
    return (row << 7) + ((chunk ^ (row & 7)) << 4);
}

template <bool DIAG>
static __device__ __forceinline__ void softmax64(const f32x4 s[4], int key0, int qrow,
                                                 float& m, float& l,
                                                 f32x4 o[4], bf16x8& pf0, bf16x8& pf1, int g) {
    const float SCL = 0.125f * 1.4426950408889634f;   // HD^-0.5 * log2(e)
    float sv[16];
#pragma unroll
    for (int ks = 0; ks < 4; ks++)
#pragma unroll
        for (int j = 0; j < 4; j++) {
            float x = s[ks][j];
            if (DIAG && (key0 + ks * 16 + 4 * g + j > qrow)) x = NINF;
            sv[ks * 4 + j] = x;
        }
    float t8[8];
#pragma unroll
    for (int i = 0; i < 8; i++) t8[i] = fmaxf(sv[i], sv[i + 8]);
#pragma unroll
    for (int i = 0; i < 4; i++) t8[i] = fmaxf(t8[i], t8[i + 4]);
    float tm = fmaxf(fmaxf(t8[0], t8[1]), fmaxf(t8[2], t8[3]));
    tm = fmaxf(tm, __shfl_xor(tm, 16));
    tm = fmaxf(tm, __shfl_xor(tm, 32));

    float msc;
    if (__all(tm <= m)) {                 // exact skip: alpha == 1 for every row
        msc = m * SCL;
    } else {
        float mnew  = fmaxf(m, tm);
        float alpha = __builtin_amdgcn_exp2f((m - mnew) * SCL);
        l *= alpha;
#pragma unroll
        for (int ch = 0; ch < 4; ch++) o[ch] *= alpha;
        m = mnew;
        msc = mnew * SCL;
    }
    float p[16];
#pragma unroll
    for (int i = 0; i < 16; i++) p[i] = __builtin_amdgcn_exp2f(__builtin_fmaf(sv[i], SCL, -msc));
    float ps0 = ((p[0] + p[1]) + (p[2] + p[3])) + ((p[4] + p[5]) + (p[6] + p[7]));
    float ps1 = ((p[8] + p[9]) + (p[10] + p[11])) + ((p[12] + p[13]) + (p[14] + p[15]));
    l += ps0 + ps1;
    union { unsigned w[4]; bf16x8 v; } q0, q1;
    asm("v_cvt_pk_bf16_f32 %0, %1, %2" : "=v"(q0.w[0]) : "v"(p[0]),  "v"(p[1]));
    asm("v_cvt_pk_bf16_f32 %0, %1, %2" : "=v"(q0.w[1]) : "v"(p[2]),  "v"(p[3]));
    asm("v_cvt_pk_bf16_f32 %0, %1, %2" : "=v"(q0.w[2]) : "v"(p[4]),  "v"(p[5]));
    asm("v_cvt_pk_bf16_f32 %0, %1, %2" : "=v"(q0.w[3]) : "v"(p[6]),  "v"(p[7]));
    asm("v_cvt_pk_bf16_f32 %0, %1, %2" : "=v"(q1.w[0]) : "v"(p[8]),  "v"(p[9]));
    asm("v_cvt_pk_bf16_f32 %0, %1, %2" : "=v"(q1.w[1]) : "v"(p[10]), "v"(p[11]));
    asm("v_cvt_pk_bf16_f32 %0, %1, %2" : "=v"(q1.w[2]) : "v"(p[12]), "v"(p[13]));
    asm("v_cvt_pk_bf16_f32 %0, %1, %2" : "=v"(q1.w[3]) : "v"(p[14]), "v"(p[15]));
    pf0 = q0.v; pf1 = q1.v;
}

__global__ __launch_bounds__(256, 4) void attn_fwd(const unsigned short* __restrict__ Q,
                                                   const unsigned short* __restrict__ Kk,
                                                   const unsigned short* __restrict__ Vt,
                                                   unsigned short* __restrict__ O) {
    __shared__ __align__(16) unsigned short Ks[2][4096];   // dbuf: 64 keys x 64 d (swizzled)
    __shared__ __align__(16) unsigned short Vs[2][4096];   // dbuf: 64 d x 64 keys (swizzled, slot-ordered)

    const int w    = threadIdx.x >> 6;
    const int lane = threadIdx.x & 63;
    const int l15  = lane & 15, g = lane >> 4;

    const int bid = blockIdx.x;
    const int x   = bid & 7;
    const int y   = (bid >> 3) & 31;
    const int q   = bid >> 8;                 // 0..3
    const int bh  = x | ((y & 3) << 3);       // 32 bh, 4 per XCD
    const int z   = y >> 2;                   // 0..7
    const int r   = (q == 0) ? z : (q == 1) ? 15 - z : (q == 2) ? 16 + z : 31 - z;
    const int b   = bh >> 4, h = bh & 15;

    const unsigned short* Qb = Q  + (size_t)bh * T_ * HD_;
    const unsigned short* Kb = Kk + (size_t)bh * T_ * HD_;
    const unsigned short* Vb = Vt + (size_t)bh * HD_ * T_;

    const int qrow = r * 64 + 16 * w + l15;
    bf16x8 qf0 = *(const bf16x8*)(Qb + (size_t)qrow * 64 + 8 * g);
    bf16x8 qf1 = *(const bf16x8*)(Qb + (size_t)qrow * 64 + 32 + 8 * g);

    f32x4 o[4];
#pragma unroll
    for (int ch = 0; ch < 4; ch++) o[ch] = (f32x4){0, 0, 0, 0};
    float m2 = NINF, lsum = 0.f;

    int off[4][2];
#pragma unroll
    for (int i = 0; i < 4; i++) {
        off[i][0] = swzb(16 * i + l15, g);
        off[i][1] = swzb(16 * i + l15, 4 + g);
    }

    const int t   = threadIdx.x;
    const int r0  = t >> 3;
    const int cs  = (t & 7) ^ (r0 & 7);
    const int t8e = t * 8;
    const unsigned short* sK = Kb + (size_t)r0 * 64 + cs * 8;     // + key0*64 per tile
    const unsigned short* sV = Vb + (size_t)r0 * 2048 + cs * 8;   // + key0 per tile

#define STAGE_TILE(bb, key0_)                                                   \
    do {                                                                        \
        GLOAD_LDS16(sK + (size_t)(key0_) * 64,        &Ks[bb][t8e]);            \
        GLOAD_LDS16(sK + (size_t)((key0_) + 32) * 64, &Ks[bb][2048 + t8e]);     \
        GLOAD_LDS16(sV + (key0_),                     &Vs[bb][t8e]);            \
        GLOAD_LDS16(sV + 32 * 2048 + (key0_),         &Vs[bb][2048 + t8e]);     \
    } while (0)

    STAGE_TILE(0, 0);
    __syncthreads();               // drains vmcnt -> tile 0 ready

#pragma unroll 2
    for (int kt = 0; kt <= r; ++kt) {
        const int key0 = kt * 64;
        const int cur  = kt & 1;
        if (kt < r) STAGE_TILE(cur ^ 1, key0 + 64);   // prefetch next tile

        const char* KsB = (const char*)&Ks[cur][0];
        const char* VsB = (const char*)&Vs[cur][0];

        bf16x8 kf[4][2], va[4][2];
#pragma unroll
        for (int i = 0; i < 4; i++) {
            kf[i][0] = *(const bf16x8*)(KsB + off[i][0]);
            kf[i][1] = *(const bf16x8*)(KsB + off[i][1]);
            va[i][0] = *(const bf16x8*)(VsB + off[i][0]);   // keys slot-ordered in memory
            va[i][1] = *(const bf16x8*)(VsB + off[i][1]);
        }

        f32x4 z4 = (f32x4){0, 0, 0, 0};
        f32x4 s[4];
#pragma unroll
        for (int ks = 0; ks < 4; ks++) {
            s[ks] = __builtin_amdgcn_mfma_f32_16x16x32_bf16(kf[ks][0], qf0, z4, 0, 0, 0);
            s[ks] = __builtin_amdgcn_mfma_f32_16x16x32_bf16(kf[ks][1], qf1, s[ks], 0, 0, 0);
        }

        bf16x8 pf0, pf1;
        if (kt == r) softmax64<true >(s, key0, qrow, m2, lsum, o, pf0, pf1, g);
        else         softmax64<false>(s, key0, qrow, m2, lsum, o, pf0, pf1, g);

#pragma unroll
        for (int ch = 0; ch < 4; ch++) {
            o[ch] = __builtin_amdgcn_mfma_f32_16x16x32_bf16(va[ch][0], pf0, o[ch], 0, 0, 0);
            o[ch] = __builtin_amdgcn_mfma_f32_16x16x32_bf16(va[ch][1], pf1, o[ch], 0, 0, 0);
        }

        __syncthreads();    // drains vmcnt (next tile staged) + read/write fence
    }
#undef STAGE_TILE

    lsum += __shfl_xor(lsum, 16);
    lsum += __shfl_xor(lsum, 32);
    float inv = 1.f / lsum;

    size_t obase = (((size_t)b * T_ + qrow) * H_ + h) * HD_;
#pragma unroll
    for (int ch = 0; ch < 4; ch++) {
        int d0 = 16 * ch + 4 * g;
        u16x4 ov;
#pragma unroll
        for (int jj = 0; jj < 4; jj++) ov[jj] = f2bf(o[ch][jj] * inv);
        *(u16x4*)(O + obase + d0) = ov;
    }
}

extern "C" void kernel_launch(void* const* d_in, const int* in_sizes, int n_in,
                              void* d_out, int out_size, void* d_ws, size_t ws_size,
                              hipStream_t stream) {
    (void)out_size;
    const float *x = nullptr, *wqkv = nullptr, *wproj = nullptr, *bproj = nullptr;
    const float *fa = nullptr, *fb = nullptr;
    for (int i = 0; i < n_in; i++) {
        switch (in_sizes[i]) {
            case 4194304: x     = (const float*)d_in[i]; break;
            case 3145728: wqkv  = (const float*)d_in[i]; break;
            case 1048576: wproj = (const float*)d_in[i]; break;
            case 1024:    bproj = (const float*)d_in[i]; break;
            case 65536:   if (!fa) fa = (const float*)d_in[i]; else fb = (const float*)d_in[i]; break;
            default: break;
        }
    }
    if (!x || !wqkv || !wproj || !bproj || !fa || !fb) return;
    if (ws_size < (size_t)48 * 1024 * 1024) return;

    char* ws = (char*)d_ws;
    const size_t MB = 1024 * 1024;
    unsigned short* xb     = (unsigned short*)(ws);            // [0,8M)
    unsigned short* wqkvb  = (unsigned short*)(ws + 8  * MB);  // [8,14M)
    unsigned short* wprojb = (unsigned short*)(ws + 14 * MB);  // [14,16M)
    unsigned short* qro    = (unsigned short*)(ws + 16 * MB);  // [16,24M)
    unsigned short* kro    = (unsigned short*)(ws + 24 * MB);  // [24,32M)
    unsigned short* vt     = (unsigned short*)(ws + 32 * MB);  // [32,40M)
    unsigned short* oat    = (unsigned short*)(ws + 40 * MB);  // [40,48M)

    convert3<<<8192, 256, 0, stream>>>(x, wqkv, wproj, xb, wqkvb, wprojb);

    gemm_qkv<<<dim3(24, 32), 256, 0, stream>>>(xb, wqkvb, fa, fb, qro, kro, vt);

    attn_fwd<<<1024, 256, 0, stream>>>(qro, kro, vt, oat);

    gemm_nt<<<dim3(8, 32), 256, 0, stream>>>(oat, wprojb, (float*)d_out, bproj,
                                             4096, 1024, 1024);
}